// Round 4
// baseline (393.603 us; speedup 1.0000x reference)
//
#include <hip/hip_runtime.h>

// MEASUREMENT ROUND: stage-1 launched TWICE (idempotent) to expose its true
// duration as the dur_us delta vs round 3 (354 us). See analysis.
//
// Stage 1: one WAVE per row (no LDS, no __syncthreads).
// Block = 256 threads = 4 waves = 4 rows; grid = B/4 = 2048 blocks.
__global__ __launch_bounds__(256) void row_check_kernel(
    const int* __restrict__ x, int* __restrict__ partial) {
  const int wave = threadIdx.x >> 6;
  const int lane = threadIdx.x & 63;
  const int row  = (blockIdx.x << 2) + wave;
  const size_t rowoff = (size_t)row << 13;            // row * 8192
  const int4* rp = (const int4*)(x + rowoff);         // 2048 int4 per row

  unsigned pres = 0;   // bit v set if token v present (clipped to [0,7])
  int last1 = -1;      // max element index where token == 1
  int rg12 = 0;        // lane 0 only: first-token/second-token penalties

  int4 buf[8];
  #pragma unroll
  for (int j = 0; j < 8; ++j) buf[j] = rp[lane + (j << 6)];

  #pragma unroll
  for (int g = 0; g < 4; ++g) {
    int4 nxt[8];
    if (g < 3) {
      #pragma unroll
      for (int j = 0; j < 8; ++j) nxt[j] = rp[lane + (((g + 1) * 8 + j) << 6)];
    }
    #pragma unroll
    for (int j = 0; j < 8; ++j) {
      const int4 v = buf[j];
      const int base = (lane + ((g * 8 + j) << 6)) << 2;  // element idx of v.x
      const int e0 = v.x, e1 = v.y, e2 = v.z, e3 = v.w;
      const int c0 = min(max(e0, 0), 7), c1 = min(max(e1, 0), 7);
      const int c2 = min(max(e2, 0), 7), c3 = min(max(e3, 0), 7);
      pres |= (1u << c0) | (1u << c1) | (1u << c2) | (1u << c3);
      last1 = max(last1, (e0 == 1) ? (base + 0) : -1);
      last1 = max(last1, (e1 == 1) ? (base + 1) : -1);
      last1 = max(last1, (e2 == 1) ? (base + 2) : -1);
      last1 = max(last1, (e3 == 1) ? (base + 3) : -1);
      if (g == 0 && j == 0 && lane == 0) {
        rg12 = ((e0 != 0) ? 4 : 0) + ((e1 != 1) ? 4 : 0);
      }
    }
    if (g < 3) {
      #pragma unroll
      for (int j = 0; j < 8; ++j) buf[j] = nxt[j];
    }
  }

  #pragma unroll
  for (int off = 32; off > 0; off >>= 1) {
    pres |= (unsigned)__shfl_down((int)pres, off);
    last1 = max(last1, __shfl_down(last1, off));
  }

  if (lane == 0) {
    const int d = 8 - __popc(pres);
    const int rg3 = d * d;
    int rg4 = 6;
    if (last1 > 0 && last1 < 8192 - 5) {
      const int* r = x + rowoff + last1;
      rg4 = (int)(r[1] != 2) + (int)(r[2] != 4) + (int)(r[3] != 5) +
            (int)(r[4] != 6) + (int)(r[5] != 3);
    }
    partial[row] = rg12 + rg3 + rg4;  // plain store, idempotent across passes
  }
}

__global__ __launch_bounds__(256) void final_reduce_kernel(
    const int* __restrict__ partial, int* __restrict__ out, int B) {
  const int t = threadIdx.x;
  int s = 0;
  for (int i = t; i < B; i += 256) s += partial[i];
  #pragma unroll
  for (int off = 32; off > 0; off >>= 1) s += __shfl_down(s, off);
  __shared__ int sw[4];
  if ((t & 63) == 0) sw[t >> 6] = s;
  __syncthreads();
  if (t == 0) out[0] = sw[0] + sw[1] + sw[2] + sw[3];
}

extern "C" void kernel_launch(void* const* d_in, const int* in_sizes, int n_in,
                              void* d_out, int out_size, void* d_ws, size_t ws_size,
                              hipStream_t stream) {
  const int* x = (const int*)d_in[0];
  const int S = 8192;
  const int B = in_sizes[0] / S;   // 8192
  int* partial = (int*)d_ws;
  int* out = (int*)d_out;
  // Pass 1 + identical pass 2: the dur_us delta vs the single-pass round
  // isolates one full stage-1 duration (discriminates fixed-overhead models).
  row_check_kernel<<<dim3(B / 4), dim3(256), 0, stream>>>(x, partial);
  row_check_kernel<<<dim3(B / 4), dim3(256), 0, stream>>>(x, partial);
  final_reduce_kernel<<<dim3(1), dim3(256), 0, stream>>>(partial, out, B);
}

// Round 5
// 354.758 us; speedup vs baseline: 1.1095x; 1.1095x over previous
//
#include <hip/hip_runtime.h>

// FINAL (revert of round-4 measurement scaffold to the round-3 single-pass
// kernel — best measured config, 354.3 us total; stage-1 itself measured at
// ~39 us via the round-4 double-launch delta = HBM roofline for the 268 MB
// mandatory read. Remaining dur_us is fixed harness stream work.)
//
// Stage 1: one WAVE per row (no LDS, no __syncthreads).
// Block = 256 threads = 4 waves = 4 rows; grid = B/4 = 2048 blocks.
__global__ __launch_bounds__(256) void row_check_kernel(
    const int* __restrict__ x, int* __restrict__ partial) {
  const int wave = threadIdx.x >> 6;
  const int lane = threadIdx.x & 63;
  const int row  = (blockIdx.x << 2) + wave;
  const size_t rowoff = (size_t)row << 13;            // row * 8192
  const int4* rp = (const int4*)(x + rowoff);         // 2048 int4 per row

  unsigned pres = 0;   // bit v set if token v present (clipped to [0,7])
  int last1 = -1;      // max element index where token == 1
  int rg12 = 0;        // lane 0 only: first-token/second-token penalties

  int4 buf[8];
  #pragma unroll
  for (int j = 0; j < 8; ++j) buf[j] = rp[lane + (j << 6)];

  #pragma unroll
  for (int g = 0; g < 4; ++g) {
    int4 nxt[8];
    if (g < 3) {
      #pragma unroll
      for (int j = 0; j < 8; ++j) nxt[j] = rp[lane + (((g + 1) * 8 + j) << 6)];
    }
    #pragma unroll
    for (int j = 0; j < 8; ++j) {
      const int4 v = buf[j];
      const int base = (lane + ((g * 8 + j) << 6)) << 2;  // element idx of v.x
      const int e0 = v.x, e1 = v.y, e2 = v.z, e3 = v.w;
      // presence uses clipped values (ref: jnp.clip(vals, 0, 7)) -> v_med3
      const int c0 = min(max(e0, 0), 7), c1 = min(max(e1, 0), 7);
      const int c2 = min(max(e2, 0), 7), c3 = min(max(e3, 0), 7);
      pres |= (1u << c0) | (1u << c1) | (1u << c2) | (1u << c3);
      // last occurrence of raw token 1 (branch-free cndmask + max)
      last1 = max(last1, (e0 == 1) ? (base + 0) : -1);
      last1 = max(last1, (e1 == 1) ? (base + 1) : -1);
      last1 = max(last1, (e2 == 1) ? (base + 2) : -1);
      last1 = max(last1, (e3 == 1) ? (base + 3) : -1);
      if (g == 0 && j == 0 && lane == 0) {
        rg12 = ((e0 != 0) ? 4 : 0) + ((e1 != 1) ? 4 : 0);
      }
    }
    if (g < 3) {
      #pragma unroll
      for (int j = 0; j < 8; ++j) buf[j] = nxt[j];
    }
  }

  // wave(64) butterfly reduce: OR for presence, max for last1
  #pragma unroll
  for (int off = 32; off > 0; off >>= 1) {
    pres |= (unsigned)__shfl_down((int)pres, off);
    last1 = max(last1, __shfl_down(last1, off));
  }

  if (lane == 0) {
    const int d = 8 - __popc(pres);
    const int rg3 = d * d;
    int rg4 = 6;  // covers last1 == -1 (no token 1), last1 == 0, last1 >= S-5
    if (last1 > 0 && last1 < 8192 - 5) {
      const int* r = x + rowoff + last1;  // row just streamed -> cache-hot
      rg4 = (int)(r[1] != 2) + (int)(r[2] != 4) + (int)(r[3] != 5) +
            (int)(r[4] != 6) + (int)(r[5] != 3);
    }
    partial[row] = rg12 + rg3 + rg4;  // plain store, no atomic
  }
}

// Stage 2: single block sums B partials and writes the scalar result
// (d_out needs no pre-zeroing).
__global__ __launch_bounds__(256) void final_reduce_kernel(
    const int* __restrict__ partial, int* __restrict__ out, int B) {
  const int t = threadIdx.x;
  int s = 0;
  for (int i = t; i < B; i += 256) s += partial[i];
  #pragma unroll
  for (int off = 32; off > 0; off >>= 1) s += __shfl_down(s, off);
  __shared__ int sw[4];
  if ((t & 63) == 0) sw[t >> 6] = s;
  __syncthreads();
  if (t == 0) out[0] = sw[0] + sw[1] + sw[2] + sw[3];
}

extern "C" void kernel_launch(void* const* d_in, const int* in_sizes, int n_in,
                              void* d_out, int out_size, void* d_ws, size_t ws_size,
                              hipStream_t stream) {
  const int* x = (const int*)d_in[0];
  const int S = 8192;
  const int B = in_sizes[0] / S;   // 8192
  int* partial = (int*)d_ws;       // B ints, fully overwritten each call
  int* out = (int*)d_out;
  row_check_kernel<<<dim3(B / 4), dim3(256), 0, stream>>>(x, partial);
  final_reduce_kernel<<<dim3(1), dim3(256), 0, stream>>>(partial, out, B);
}